// Round 1
// baseline (651.019 us; speedup 1.0000x reference)
//
#include <hip/hip_runtime.h>
#include <hip/hip_bf16.h>

// Problem constants (fixed by reference): D=4, B=2, S=4096, DIN_S=512, DOUT_S=2048
#define D_   4
#define M_   8192      // B*S
#define K_   2048      // D*DIN_S
#define N_   2048      // DOUT_S
#define DIN  512

typedef __attribute__((ext_vector_type(8))) short  short8v;   // 8 bf16 = 4 VGPRs (MFMA A/B frag)
typedef __attribute__((ext_vector_type(4))) float  f32x4;     // MFMA C/D frag

// fp32 -> bf16, round-to-nearest-even (inputs are finite gaussians; no NaN path needed)
__device__ __forceinline__ unsigned short f2bf(float f) {
  union { float f; unsigned int u; } v; v.f = f;
  unsigned int u = v.u;
  return (unsigned short)((u + 0x7fffu + ((u >> 16) & 1u)) >> 16);
}

// --- Kernel 1: x [i][m][k] fp32 -> A [m][i*512+k] bf16 (row-major M x K) -----
// tid = m*256 + i*64 + kg ; each thread moves 8 contiguous k's.
// Reads float4 x2 coalesced, writes 16B coalesced (out offset == tid*16B).
__global__ __launch_bounds__(256) void convert_x_kernel(const float* __restrict__ x,
                                                        unsigned short* __restrict__ A) {
  unsigned int tid = blockIdx.x * 256u + threadIdx.x;   // [0, M_*K_/8)
  unsigned int kg  = tid & 63u;
  unsigned int i   = (tid >> 6) & 3u;
  unsigned int m   = tid >> 8;
  const float4* src = (const float4*)(x + (size_t)i * ((size_t)M_ * DIN)
                                        + (size_t)m * DIN + (size_t)kg * 8);
  float4 a = src[0];
  float4 b = src[1];
  uint4 pk;
  pk.x = (unsigned int)f2bf(a.x) | ((unsigned int)f2bf(a.y) << 16);
  pk.y = (unsigned int)f2bf(a.z) | ((unsigned int)f2bf(a.w) << 16);
  pk.z = (unsigned int)f2bf(b.x) | ((unsigned int)f2bf(b.y) << 16);
  pk.w = (unsigned int)f2bf(b.z) | ((unsigned int)f2bf(b.w) << 16);
  *(uint4*)(A + (size_t)tid * 8) = pk;
}

// --- Kernel 2: W [d][K][N] fp32 -> Wt [d][N][K] bf16 (transpose + cast) ------
// 32x32 tiles through LDS (33-float pad: conflict-free column reads).
__global__ __launch_bounds__(256) void transpose_w_kernel(const float* __restrict__ W,
                                                          unsigned short* __restrict__ Wt) {
  __shared__ float tile[32][33];
  const int d  = blockIdx.z;
  const int o0 = blockIdx.x * 32;   // N (col in, row out)
  const int k0 = blockIdx.y * 32;   // K (row in, col out)
  const int tx = threadIdx.x;       // 0..31
  const int ty = threadIdx.y;       // 0..7
  const float* src = W + (size_t)d * ((size_t)K_ * N_);
  #pragma unroll
  for (int j = 0; j < 32; j += 8)
    tile[ty + j][tx] = src[(size_t)(k0 + ty + j) * N_ + (o0 + tx)];
  __syncthreads();
  unsigned short* dst = Wt + (size_t)d * ((size_t)N_ * K_);
  #pragma unroll
  for (int j = 0; j < 32; j += 8)
    dst[(size_t)(o0 + ty + j) * K_ + (k0 + tx)] = f2bf(tile[tx][ty + j]);
}

// --- Kernel 3: bf16 MFMA GEMM, m97 structure ---------------------------------
// 128x128 tile, 256 thr (4 waves, 2x2 of 64x64), BK=32, single-buffered LDS,
// global_load_lds width=16 staging (LDS layout MUST be unpadded [row][32] —
// dest is wave-uniform-base + lane*16B).
#define GLL16(gp, lp)                                                              \
  __builtin_amdgcn_global_load_lds(                                               \
      (const __attribute__((address_space(1))) void*)(gp),                        \
      (__attribute__((address_space(3))) void*)(lp), 16, 0, 0)

__global__ __launch_bounds__(256) void gemm_kernel(const unsigned short* __restrict__ A,
                                                   const unsigned short* __restrict__ Bt,
                                                   const float* __restrict__ bias,
                                                   float* __restrict__ C) {
  __shared__ unsigned short sA[128 * 32];   // [m][k] 8 KB
  __shared__ unsigned short sB[128 * 32];   // [n][k] 8 KB
  const int tid   = threadIdx.x;
  const int wave  = tid >> 6;
  const int lane  = tid & 63;
  const int d     = blockIdx.z;
  const int tileN = blockIdx.x * 128;
  const int tileM = blockIdx.y * 128;

  // Staging: each wave owns 32 rows (2 x global_load_lds of 1024B = 16 rows each).
  const int srow = lane >> 2;          // row within 16-row chunk
  const int scol = (lane & 3) * 8;     // 8 bf16 = 16 B per lane
  const unsigned short* gA0 = A + (size_t)(tileM + wave * 32 + srow) * K_ + scol;
  const unsigned short* gA1 = gA0 + (size_t)16 * K_;
  const unsigned short* gB0 = Bt + (size_t)d * ((size_t)N_ * K_)
                                 + (size_t)(tileN + wave * 32 + srow) * K_ + scol;
  const unsigned short* gB1 = gB0 + (size_t)16 * K_;
  unsigned short* lA0 = sA + (wave * 32) * 32;        // wave-uniform LDS bases
  unsigned short* lA1 = sA + (wave * 32 + 16) * 32;
  unsigned short* lB0 = sB + (wave * 32) * 32;
  unsigned short* lB1 = sB + (wave * 32 + 16) * 32;

  // Fragment addressing: A-frag lane l -> m = l&15, k = (l>>4)*8..+8 (ds_read_b128)
  const int wm   = (wave >> 1) * 64;
  const int wn   = (wave & 1) * 64;
  const int fr   = lane & 15;
  const int koff = (lane >> 4) * 8;

  f32x4 acc[4][4];
  #pragma unroll
  for (int i = 0; i < 4; i++)
    #pragma unroll
    for (int j = 0; j < 4; j++)
      acc[i][j] = (f32x4){0.f, 0.f, 0.f, 0.f};

  for (int k0 = 0; k0 < K_; k0 += 32) {
    GLL16(gA0 + k0, lA0);
    GLL16(gA1 + k0, lA1);
    GLL16(gB0 + k0, lB0);
    GLL16(gB1 + k0, lB1);
    __syncthreads();   // compiler emits s_waitcnt vmcnt(0) before s_barrier

    short8v af[4], bfv[4];
    #pragma unroll
    for (int mi = 0; mi < 4; mi++)
      af[mi] = *(const short8v*)(sA + (wm + mi * 16 + fr) * 32 + koff);
    #pragma unroll
    for (int ni = 0; ni < 4; ni++)
      bfv[ni] = *(const short8v*)(sB + (wn + ni * 16 + fr) * 32 + koff);
    #pragma unroll
    for (int mi = 0; mi < 4; mi++)
      #pragma unroll
      for (int ni = 0; ni < 4; ni++)
        acc[mi][ni] = __builtin_amdgcn_mfma_f32_16x16x32_bf16(af[mi], bfv[ni],
                                                              acc[mi][ni], 0, 0, 0);
    __syncthreads();
  }

  // Epilogue: C/D layout col=lane&15, row=(lane>>4)*4+reg [m89/m91-verified]
  float* Cd       = C + (size_t)d * ((size_t)M_ * N_);
  const float* bd = bias + d * N_;
  #pragma unroll
  for (int ni = 0; ni < 4; ni++) {
    const int col  = tileN + wn + ni * 16 + fr;
    const float bv = bd[col];
    #pragma unroll
    for (int mi = 0; mi < 4; mi++) {
      const int row0 = tileM + wm + mi * 16 + (lane >> 4) * 4;
      #pragma unroll
      for (int r = 0; r < 4; r++)
        Cd[(size_t)(row0 + r) * N_ + col] = acc[mi][ni][r] + bv;
    }
  }
}

// --- Fallback: naive fp32 (only if d_ws is too small; correctness insurance) -
__global__ void naive_kernel(const float* __restrict__ x, const float* __restrict__ W,
                             const float* __restrict__ bias, float* __restrict__ y) {
  long idx = (long)blockIdx.x * blockDim.x + threadIdx.x;
  if (idx >= (long)D_ * M_ * N_) return;
  int  n = (int)(idx % N_);
  long t = idx / N_;
  int  m = (int)(t % M_);
  int  d = (int)(t / M_);
  float acc = bias[d * N_ + n];
  const float* wd = W + (size_t)d * ((size_t)K_ * N_);
  for (int i = 0; i < D_; i++) {
    const float* xr = x + (size_t)i * ((size_t)M_ * DIN) + (size_t)m * DIN;
    const float* wr = wd + (size_t)i * ((size_t)DIN * N_) + n;
    #pragma unroll 4
    for (int k = 0; k < DIN; k++) acc += xr[k] * wr[(size_t)k * N_];
  }
  y[idx] = acc;
}

extern "C" void kernel_launch(void* const* d_in, const int* in_sizes, int n_in,
                              void* d_out, int out_size, void* d_ws, size_t ws_size,
                              hipStream_t stream) {
  const float* x    = (const float*)d_in[0];   // [4][2][4096][512] fp32
  const float* W    = (const float*)d_in[1];   // [4][4][512][2048] fp32
  const float* bias = (const float*)d_in[2];   // [4][2048] fp32
  float* out        = (float*)d_out;           // [4][2][4096][2048] fp32

  const size_t a_elems  = (size_t)M_ * K_;             // 16.7M bf16 = 32 MiB
  const size_t wt_elems = (size_t)D_ * N_ * K_;        // 16.7M bf16 = 32 MiB
  const size_t need     = (a_elems + wt_elems) * sizeof(unsigned short);

  if (ws_size >= need) {
    unsigned short* Abf = (unsigned short*)d_ws;
    unsigned short* Wt  = Abf + a_elems;

    convert_x_kernel<<<(M_ * K_ / 8) / 256, 256, 0, stream>>>(x, Abf);

    dim3 tgrid(N_ / 32, K_ / 32, D_);
    transpose_w_kernel<<<tgrid, dim3(32, 8), 0, stream>>>(W, Wt);

    dim3 ggrid(N_ / 128, M_ / 128, D_);   // (16, 64, 4) = 4096 blocks
    gemm_kernel<<<ggrid, 256, 0, stream>>>(Abf, Wt, bias, out);
  } else {
    long total = (long)D_ * M_ * N_;
    naive_kernel<<<(unsigned int)((total + 255) / 256), 256, 0, stream>>>(x, W, bias, out);
  }
}

// Round 2
// 649.593 us; speedup vs baseline: 1.0022x; 1.0022x over previous
//
#include <hip/hip_runtime.h>
#include <hip/hip_bf16.h>

// Problem constants (fixed by reference): D=4, B=2, S=4096, DIN_S=512, DOUT_S=2048
#define D_   4
#define M_   8192      // B*S
#define K_   2048      // D*DIN_S
#define N_   2048      // DOUT_S
#define DIN  512

typedef __attribute__((ext_vector_type(8))) short  short8v;   // 8 bf16 = 4 VGPRs (MFMA A/B frag)
typedef __attribute__((ext_vector_type(4))) float  f32x4;     // MFMA C/D frag

// fp32 -> bf16, round-to-nearest-even
__device__ __forceinline__ unsigned short f2bf(float f) {
  union { float f; unsigned int u; } v; v.f = f;
  unsigned int u = v.u;
  return (unsigned short)((u + 0x7fffu + ((u >> 16) & 1u)) >> 16);
}

// --- Kernel 1: x [i][m][k] fp32 -> A [m][i*512+k] bf16 (row-major M x K) -----
// tid = m*256 + i*64 + kg ; each thread moves 8 contiguous k's.
__global__ __launch_bounds__(256) void convert_x_kernel(const float* __restrict__ x,
                                                        unsigned short* __restrict__ A) {
  unsigned int tid = blockIdx.x * 256u + threadIdx.x;   // [0, M_*K_/8)
  unsigned int kg  = tid & 63u;
  unsigned int i   = (tid >> 6) & 3u;
  unsigned int m   = tid >> 8;
  const float4* src = (const float4*)(x + (size_t)i * ((size_t)M_ * DIN)
                                        + (size_t)m * DIN + (size_t)kg * 8);
  float4 a = src[0];
  float4 b = src[1];
  uint4 pk;
  pk.x = (unsigned int)f2bf(a.x) | ((unsigned int)f2bf(a.y) << 16);
  pk.y = (unsigned int)f2bf(a.z) | ((unsigned int)f2bf(a.w) << 16);
  pk.z = (unsigned int)f2bf(b.x) | ((unsigned int)f2bf(b.y) << 16);
  pk.w = (unsigned int)f2bf(b.z) | ((unsigned int)f2bf(b.w) << 16);
  *(uint4*)(A + (size_t)tid * 8) = pk;
}

// --- Kernel 2: W [d][K][N] fp32 -> Wt [d][N][K] bf16 (transpose + cast) ------
// 64x64 tiles; float4 coalesced reads, ushort8 (16B) coalesced writes.
// Old version did 16.7M scalar 2-byte stores (~250us); this does 2.1M 16-byte.
__global__ __launch_bounds__(256) void transpose_w_kernel(const float* __restrict__ W,
                                                          unsigned short* __restrict__ Wt) {
  __shared__ float tile[64][65];   // +1 pad: column reads ~2-way max (free)
  const int d  = blockIdx.z;
  const int k0 = blockIdx.x * 64;
  const int o0 = blockIdx.y * 64;
  const int t  = threadIdx.x;
  const float* src = W + (size_t)d * ((size_t)K_ * N_) + (size_t)k0 * N_ + o0;
  const int c4 = (t & 15) * 4;    // float4 col
  const int r  = t >> 4;          // row 0..15, step 16
  #pragma unroll
  for (int j = 0; j < 64; j += 16) {
    float4 v = *(const float4*)(src + (size_t)(r + j) * N_ + c4);
    tile[r + j][c4 + 0] = v.x; tile[r + j][c4 + 1] = v.y;
    tile[r + j][c4 + 2] = v.z; tile[r + j][c4 + 3] = v.w;
  }
  __syncthreads();
  unsigned short* dst = Wt + (size_t)d * ((size_t)N_ * K_);
  const int kk = (t & 7) * 8;     // 8 consecutive k per thread
  const int oo = t >> 3;          // o row 0..31, 2 passes
  #pragma unroll
  for (int p = 0; p < 64; p += 32) {
    const int o = oo + p;
    unsigned short tmp[8];
    #pragma unroll
    for (int i = 0; i < 8; i++) tmp[i] = f2bf(tile[kk + i][o]);
    *(uint4*)(dst + (size_t)(o0 + o) * K_ + k0 + kk) = *(uint4*)tmp;
  }
}

// --- Kernel 3: bf16 MFMA GEMM, m97 structure + XOR-swizzled LDS --------------
// 128x128 tile, 256 thr (4 waves, 2x2 of 64x64), BK=32, single-buffered LDS.
// global_load_lds width=16; LDS layout is lane-order (wave-uniform base +
// lane*16B), so bank-conflict avoidance is done by permuting WHICH (row,q)
// each lane loads: lane -> (row = lane>>2, q = (lane&3) ^ ((lane>>3)&3)).
// 4-lane groups still cover one contiguous 64B row segment (coalescing kept);
// fragment reads land 2 lanes/bank-quad (2-way = free) instead of 8-way.
#define GLL16(gp, lp)                                                              \
  __builtin_amdgcn_global_load_lds(                                               \
      (const __attribute__((address_space(1))) void*)(gp),                        \
      (__attribute__((address_space(3))) void*)(lp), 16, 0, 0)

__global__ __launch_bounds__(256) void gemm_kernel(const unsigned short* __restrict__ A,
                                                   const unsigned short* __restrict__ Bt,
                                                   const float* __restrict__ bias,
                                                   float* __restrict__ C) {
  __shared__ unsigned short sA[128 * 32];   // [16-row chunk][swizzled lane-order] 8 KB
  __shared__ unsigned short sB[128 * 32];   // 8 KB
  const int tid   = threadIdx.x;
  const int wave  = tid >> 6;
  const int lane  = tid & 63;
  const int d     = blockIdx.z;
  const int tileN = blockIdx.x * 128;
  const int tileM = blockIdx.y * 128;

  // Staging: swizzled lane mapping (see comment above).
  const int srow = lane >> 2;                              // row within 16-row chunk
  const int scol = ((lane & 3) ^ ((lane >> 3) & 3)) * 8;   // swizzled 8-elem chunk
  const unsigned short* gA0 = A + (size_t)(tileM + wave * 32 + srow) * K_ + scol;
  const unsigned short* gA1 = gA0 + (size_t)16 * K_;
  const unsigned short* gB0 = Bt + (size_t)d * ((size_t)N_ * K_)
                                 + (size_t)(tileN + wave * 32 + srow) * K_ + scol;
  const unsigned short* gB1 = gB0 + (size_t)16 * K_;
  unsigned short* lA0 = sA + (wave * 32) * 32;        // wave-uniform LDS bases
  unsigned short* lA1 = sA + (wave * 32 + 16) * 32;
  unsigned short* lB0 = sB + (wave * 32) * 32;
  unsigned short* lB1 = sB + (wave * 32 + 16) * 32;

  // Fragment addressing: lane (fr, qw) wants (row=..+fr, k-chunk qw);
  // staged LDS slot for (r,q) is r*64B + (q ^ ((r>>1)&3))*16B -> fcol is a
  // lane constant (same instruction count as unswizzled).
  const int wm   = (wave >> 1) * 64;
  const int wn   = (wave & 1) * 64;
  const int fr   = lane & 15;
  const int qw   = lane >> 4;
  const int fcol = (qw ^ ((fr >> 1) & 3)) * 8;   // element offset within row

  f32x4 acc[4][4];
  #pragma unroll
  for (int i = 0; i < 4; i++)
    #pragma unroll
    for (int j = 0; j < 4; j++)
      acc[i][j] = (f32x4){0.f, 0.f, 0.f, 0.f};

  for (int k0 = 0; k0 < K_; k0 += 32) {
    GLL16(gA0 + k0, lA0);
    GLL16(gA1 + k0, lA1);
    GLL16(gB0 + k0, lB0);
    GLL16(gB1 + k0, lB1);
    __syncthreads();

    short8v af[4], bfv[4];
    #pragma unroll
    for (int mi = 0; mi < 4; mi++)
      af[mi] = *(const short8v*)(sA + (wm + mi * 16 + fr) * 32 + fcol);
    #pragma unroll
    for (int ni = 0; ni < 4; ni++)
      bfv[ni] = *(const short8v*)(sB + (wn + ni * 16 + fr) * 32 + fcol);
    #pragma unroll
    for (int mi = 0; mi < 4; mi++)
      #pragma unroll
      for (int ni = 0; ni < 4; ni++)
        acc[mi][ni] = __builtin_amdgcn_mfma_f32_16x16x32_bf16(af[mi], bfv[ni],
                                                              acc[mi][ni], 0, 0, 0);
    __syncthreads();
  }

  // Epilogue: C/D layout col=lane&15, row=(lane>>4)*4+reg [m89/m91-verified]
  float* Cd       = C + (size_t)d * ((size_t)M_ * N_);
  const float* bd = bias + d * N_;
  #pragma unroll
  for (int ni = 0; ni < 4; ni++) {
    const int col  = tileN + wn + ni * 16 + fr;
    const float bv = bd[col];
    #pragma unroll
    for (int mi = 0; mi < 4; mi++) {
      const int row0 = tileM + wm + mi * 16 + qw * 4;
      #pragma unroll
      for (int r = 0; r < 4; r++)
        Cd[(size_t)(row0 + r) * N_ + col] = acc[mi][ni][r] + bv;
    }
  }
}

// --- Fallback: naive fp32 (only if d_ws is too small) ------------------------
__global__ void naive_kernel(const float* __restrict__ x, const float* __restrict__ W,
                             const float* __restrict__ bias, float* __restrict__ y) {
  long idx = (long)blockIdx.x * blockDim.x + threadIdx.x;
  if (idx >= (long)D_ * M_ * N_) return;
  int  n = (int)(idx % N_);
  long t = idx / N_;
  int  m = (int)(t % M_);
  int  d = (int)(t / M_);
  float acc = bias[d * N_ + n];
  const float* wd = W + (size_t)d * ((size_t)K_ * N_);
  for (int i = 0; i < D_; i++) {
    const float* xr = x + (size_t)i * ((size_t)M_ * DIN) + (size_t)m * DIN;
    const float* wr = wd + (size_t)i * ((size_t)DIN * N_) + n;
    #pragma unroll 4
    for (int k = 0; k < DIN; k++) acc += xr[k] * wr[(size_t)k * N_];
  }
  y[idx] = acc;
}

extern "C" void kernel_launch(void* const* d_in, const int* in_sizes, int n_in,
                              void* d_out, int out_size, void* d_ws, size_t ws_size,
                              hipStream_t stream) {
  const float* x    = (const float*)d_in[0];   // [4][2][4096][512] fp32
  const float* W    = (const float*)d_in[1];   // [4][4][512][2048] fp32
  const float* bias = (const float*)d_in[2];   // [4][2048] fp32
  float* out        = (float*)d_out;           // [4][2][4096][2048] fp32

  const size_t a_elems  = (size_t)M_ * K_;
  const size_t wt_elems = (size_t)D_ * N_ * K_;
  const size_t need     = (a_elems + wt_elems) * sizeof(unsigned short);

  if (ws_size >= need) {
    unsigned short* Abf = (unsigned short*)d_ws;
    unsigned short* Wt  = Abf + a_elems;

    convert_x_kernel<<<(M_ * K_ / 8) / 256, 256, 0, stream>>>(x, Abf);

    dim3 tgrid(K_ / 64, N_ / 64, D_);   // (32, 32, 4)
    transpose_w_kernel<<<tgrid, 256, 0, stream>>>(W, Wt);

    dim3 ggrid(N_ / 128, M_ / 128, D_); // (16, 64, 4) = 4096 blocks
    gemm_kernel<<<ggrid, 256, 0, stream>>>(Abf, Wt, bias, out);
  } else {
    long total = (long)D_ * M_ * N_;
    naive_kernel<<<(unsigned int)((total + 255) / 256), 256, 0, stream>>>(x, W, bias, out);
  }
}

// Round 3
// 616.708 us; speedup vs baseline: 1.0556x; 1.0533x over previous
//
#include <hip/hip_runtime.h>
#include <hip/hip_bf16.h>

// Problem constants (fixed by reference): D=4, B=2, S=4096, DIN_S=512, DOUT_S=2048
#define D_   4
#define M_   8192      // B*S
#define K_   2048      // D*DIN_S
#define N_   2048      // DOUT_S
#define DIN  512

typedef __attribute__((ext_vector_type(8))) short  short8v;   // 8 bf16 = 4 VGPRs (MFMA A/B frag)
typedef __attribute__((ext_vector_type(4))) float  f32x4;     // MFMA C/D frag

// fp32 -> bf16, round-to-nearest-even
__device__ __forceinline__ unsigned short f2bf(float f) {
  union { float f; unsigned int u; } v; v.f = f;
  unsigned int u = v.u;
  return (unsigned short)((u + 0x7fffu + ((u >> 16) & 1u)) >> 16);
}

// --- Kernel 1: x [i][m][k] fp32 -> A [m][i*512+k] bf16 (row-major M x K) -----
__global__ __launch_bounds__(256) void convert_x_kernel(const float* __restrict__ x,
                                                        unsigned short* __restrict__ A) {
  unsigned int tid = blockIdx.x * 256u + threadIdx.x;   // [0, M_*K_/8)
  unsigned int kg  = tid & 63u;
  unsigned int i   = (tid >> 6) & 3u;
  unsigned int m   = tid >> 8;
  const float4* src = (const float4*)(x + (size_t)i * ((size_t)M_ * DIN)
                                        + (size_t)m * DIN + (size_t)kg * 8);
  float4 a = src[0];
  float4 b = src[1];
  uint4 pk;
  pk.x = (unsigned int)f2bf(a.x) | ((unsigned int)f2bf(a.y) << 16);
  pk.y = (unsigned int)f2bf(a.z) | ((unsigned int)f2bf(a.w) << 16);
  pk.z = (unsigned int)f2bf(b.x) | ((unsigned int)f2bf(b.y) << 16);
  pk.w = (unsigned int)f2bf(b.z) | ((unsigned int)f2bf(b.w) << 16);
  *(uint4*)(A + (size_t)tid * 8) = pk;
}

// --- Kernel 2: W [d][K][N] fp32 -> Wt [d][N][K] bf16 (transpose + cast) ------
// 64x64 tiles; float4 coalesced reads, ushort8 (16B) coalesced writes.
__global__ __launch_bounds__(256) void transpose_w_kernel(const float* __restrict__ W,
                                                          unsigned short* __restrict__ Wt) {
  __shared__ float tile[64][65];
  const int d  = blockIdx.z;
  const int k0 = blockIdx.x * 64;
  const int o0 = blockIdx.y * 64;
  const int t  = threadIdx.x;
  const float* src = W + (size_t)d * ((size_t)K_ * N_) + (size_t)k0 * N_ + o0;
  const int c4 = (t & 15) * 4;
  const int r  = t >> 4;
  #pragma unroll
  for (int j = 0; j < 64; j += 16) {
    float4 v = *(const float4*)(src + (size_t)(r + j) * N_ + c4);
    tile[r + j][c4 + 0] = v.x; tile[r + j][c4 + 1] = v.y;
    tile[r + j][c4 + 2] = v.z; tile[r + j][c4 + 3] = v.w;
  }
  __syncthreads();
  unsigned short* dst = Wt + (size_t)d * ((size_t)N_ * K_);
  const int kk = (t & 7) * 8;
  const int oo = t >> 3;
  #pragma unroll
  for (int p = 0; p < 64; p += 32) {
    const int o = oo + p;
    unsigned short tmp[8];
    #pragma unroll
    for (int i = 0; i < 8; i++) tmp[i] = f2bf(tile[kk + i][o]);
    *(uint4*)(dst + (size_t)(o0 + o) * K_ + k0 + kk) = *(uint4*)tmp;
  }
}

// --- Kernel 3: bf16 MFMA GEMM --------------------------------------------------
// 128x128 tile, 256 thr (4 waves, 2x2 of 64x64), BK=64 (32 MFMA per wave per
// barrier — AITER-density to amortize the vmcnt(0)+s_barrier drain).
// LDS rows are 64 bf16 = 128 B = 8 chunks of 16 B. global_load_lds dest is
// wave-uniform-base + lane*16B, so conflict avoidance is done by permuting
// WHICH chunk each lane loads: lane -> (row=lane>>3, chunk=(lane&7)^(lane>>3)).
// 8-lane groups still cover one contiguous 128 B row (coalescing kept);
// fragment ds_read_b128 spreads 8 lanes per bank-quad = the b128 minimum.
// Block swizzle: XCD k (= linear id % 8, heuristic) only touches tileN pair
// {2k,2k+1} -> 1 MiB Wt working set per XCD L2; 16 consecutive blocks share
// one A stripe (L3-hot).
#define GLL16(gp, lp)                                                              \
  __builtin_amdgcn_global_load_lds(                                               \
      (const __attribute__((address_space(1))) void*)(gp),                        \
      (__attribute__((address_space(3))) void*)(lp), 16, 0, 0)

__global__ __launch_bounds__(256) void gemm_kernel(const unsigned short* __restrict__ A,
                                                   const unsigned short* __restrict__ Bt,
                                                   const float* __restrict__ bias,
                                                   float* __restrict__ C) {
  __shared__ unsigned short sA[128 * 64];   // 16 KB
  __shared__ unsigned short sB[128 * 64];   // 16 KB
  const int tid   = threadIdx.x;
  const int wave  = tid >> 6;
  const int lane  = tid & 63;
  const int d     = blockIdx.z;

  // XCD-aware swizzle (performance heuristic only; any bijection is correct)
  const int lin   = blockIdx.y * 16 + blockIdx.x;   // 0..1023 per d
  const int xcd   = lin & 7;
  const int t     = lin >> 3;                       // 0..127
  const int tileN = (xcd * 2 + (t & 1)) * 128;
  const int tileM = (t >> 1) * 128;

  // Staging lane mapping: row = lane>>3 (8 rows/GLL), chunk = (lane&7)^(lane>>3)
  const int srow = lane >> 3;
  const int scol = ((lane & 7) ^ srow) * 8;         // element offset in 64-elem row
  const unsigned short* gA = A + (size_t)(tileM + wave * 32 + srow) * K_ + scol;
  const unsigned short* gB = Bt + (size_t)d * ((size_t)N_ * K_)
                                + (size_t)(tileN + wave * 32 + srow) * K_ + scol;
  unsigned short* lA = sA + (wave * 32) * 64;       // wave-uniform LDS bases
  unsigned short* lB = sB + (wave * 32) * 64;

  // Fragment addressing: lane (fr = lane&15, qw = lane>>4) reads row fr,
  // chunk c = kstep*4+qw staged at slot c^(fr&7).
  const int wm   = (wave >> 1) * 64;
  const int wn   = (wave & 1) * 64;
  const int fr   = lane & 15;
  const int qw   = lane >> 4;
  const int fc0  = (qw ^ (fr & 7)) * 8;             // kstep 0 chunk slot (elems)
  // kstep 1 slot = ((4+qw)^(fr&7))*8 = fc0 ^ 32

  f32x4 acc[4][4];
  #pragma unroll
  for (int i = 0; i < 4; i++)
    #pragma unroll
    for (int j = 0; j < 4; j++)
      acc[i][j] = (f32x4){0.f, 0.f, 0.f, 0.f};

  for (int k0 = 0; k0 < K_; k0 += 64) {
    #pragma unroll
    for (int j = 0; j < 4; j++) {                   // 8 rows per GLL, 32 rows/wave
      GLL16(gA + (size_t)j * 8 * K_ + k0, lA + j * 8 * 64);
      GLL16(gB + (size_t)j * 8 * K_ + k0, lB + j * 8 * 64);
    }
    __syncthreads();

    #pragma unroll
    for (int ks = 0; ks < 2; ks++) {
      const int fc = fc0 ^ (ks * 32);
      short8v af[4], bfv[4];
      #pragma unroll
      for (int mi = 0; mi < 4; mi++)
        af[mi] = *(const short8v*)(sA + (wm + mi * 16 + fr) * 64 + fc);
      #pragma unroll
      for (int ni = 0; ni < 4; ni++)
        bfv[ni] = *(const short8v*)(sB + (wn + ni * 16 + fr) * 64 + fc);
      #pragma unroll
      for (int mi = 0; mi < 4; mi++)
        #pragma unroll
        for (int ni = 0; ni < 4; ni++)
          acc[mi][ni] = __builtin_amdgcn_mfma_f32_16x16x32_bf16(af[mi], bfv[ni],
                                                                acc[mi][ni], 0, 0, 0);
    }
    __syncthreads();
  }

  // Epilogue: C/D layout col=lane&15, row=(lane>>4)*4+reg [m89/m91-verified]
  float* Cd       = C + (size_t)d * ((size_t)M_ * N_);
  const float* bd = bias + d * N_;
  #pragma unroll
  for (int ni = 0; ni < 4; ni++) {
    const int col  = tileN + wn + ni * 16 + fr;
    const float bv = bd[col];
    #pragma unroll
    for (int mi = 0; mi < 4; mi++) {
      const int row0 = tileM + wm + mi * 16 + qw * 4;
      #pragma unroll
      for (int r = 0; r < 4; r++)
        Cd[(size_t)(row0 + r) * N_ + col] = acc[mi][ni][r] + bv;
    }
  }
}

// --- Fallback: naive fp32 (only if d_ws is too small) ------------------------
__global__ void naive_kernel(const float* __restrict__ x, const float* __restrict__ W,
                             const float* __restrict__ bias, float* __restrict__ y) {
  long idx = (long)blockIdx.x * blockDim.x + threadIdx.x;
  if (idx >= (long)D_ * M_ * N_) return;
  int  n = (int)(idx % N_);
  long t = idx / N_;
  int  m = (int)(t % M_);
  int  d = (int)(t / M_);
  float acc = bias[d * N_ + n];
  const float* wd = W + (size_t)d * ((size_t)K_ * N_);
  for (int i = 0; i < D_; i++) {
    const float* xr = x + (size_t)i * ((size_t)M_ * DIN) + (size_t)m * DIN;
    const float* wr = wd + (size_t)i * ((size_t)DIN * N_) + n;
    #pragma unroll 4
    for (int k = 0; k < DIN; k++) acc += xr[k] * wr[(size_t)k * N_];
  }
  y[idx] = acc;
}

extern "C" void kernel_launch(void* const* d_in, const int* in_sizes, int n_in,
                              void* d_out, int out_size, void* d_ws, size_t ws_size,
                              hipStream_t stream) {
  const float* x    = (const float*)d_in[0];   // [4][2][4096][512] fp32
  const float* W    = (const float*)d_in[1];   // [4][4][512][2048] fp32
  const float* bias = (const float*)d_in[2];   // [4][2048] fp32
  float* out        = (float*)d_out;           // [4][2][4096][2048] fp32

  const size_t a_elems  = (size_t)M_ * K_;
  const size_t wt_elems = (size_t)D_ * N_ * K_;
  const size_t need     = (a_elems + wt_elems) * sizeof(unsigned short);

  if (ws_size >= need) {
    unsigned short* Abf = (unsigned short*)d_ws;
    unsigned short* Wt  = Abf + a_elems;

    convert_x_kernel<<<(M_ * K_ / 8) / 256, 256, 0, stream>>>(x, Abf);

    dim3 tgrid(K_ / 64, N_ / 64, D_);   // (32, 32, 4)
    transpose_w_kernel<<<tgrid, 256, 0, stream>>>(W, Wt);

    dim3 ggrid(N_ / 128, M_ / 128, D_); // (16, 64, 4) = 4096 blocks
    gemm_kernel<<<ggrid, 256, 0, stream>>>(Abf, Wt, bias, out);
  } else {
    long total = (long)D_ * M_ * N_;
    naive_kernel<<<(unsigned int)((total + 255) / 256), 256, 0, stream>>>(x, W, bias, out);
  }
}